// Round 7
// baseline (249.338 us; speedup 1.0000x reference)
//
#include <hip/hip_runtime.h>
#include <stdint.h>

// Problem constants: B=8, N=1024, IN_F=1024, E=256, H=4, A=64
typedef __attribute__((ext_vector_type(8))) short short8;
typedef __attribute__((ext_vector_type(4))) float f32x4;
typedef __attribute__((ext_vector_type(16))) float f32x16;

// WhF frag-tile layout (canonical, used by k1 epilogue, k1b, k2):
//   element (hb, e, m), e in [0,256), m in [0,1024):
//   et=e>>5, e31=e&31, m16=m>>4, l5=(m>>3)&1, m7=m&7
//   u16 idx = ((hb*8+et)*64 + m16)*512 + (l5*32+e31)*8 + m7
// => one (et,m16) tile is 1KB contiguous in MFMA-B lane order (lane=l5*32+e31).

__device__ __forceinline__ float b2f(unsigned short u) {
    union { unsigned int i; float f; } v; v.i = ((unsigned int)u) << 16; return v.f;
}
__device__ __forceinline__ unsigned short f2b(float f) {
    union { float f; unsigned int i; } v; v.f = f;
    unsigned int u = v.i;
    u = (u + 0x7FFFu + ((u >> 16) & 1u)) >> 16;
    return (unsigned short)u;
}
__device__ __forceinline__ void glds16(const void* g, const void* l) {
    __builtin_amdgcn_global_load_lds(
        (const __attribute__((address_space(1))) unsigned int*)g,
        (__attribute__((address_space(3))) unsigned int*)l, 16, 0, 0);
}

__device__ __forceinline__ void cvt8(const void* in, unsigned short* out,
                                     int f, int grp) {
    if (f) {
        ((ushort4*)out)[grp * 2]     = ((const ushort4*)in)[grp * 2];
        ((ushort4*)out)[grp * 2 + 1] = ((const ushort4*)in)[grp * 2 + 1];
    } else {
        const float4* p = (const float4*)in + (size_t)grp * 2;
        float4 a = p[0], b = p[1];
        ushort4 o0, o1;
        o0.x = f2b(a.x); o0.y = f2b(a.y); o0.z = f2b(a.z); o0.w = f2b(a.w);
        o1.x = f2b(b.x); o1.y = f2b(b.y); o1.z = f2b(b.z); o1.w = f2b(b.w);
        ((ushort4*)out)[grp * 2]     = o0;
        ((ushort4*)out)[grp * 2 + 1] = o1;
    }
}

// prep_small: dtype detect (wave 0) + convert a1/a2/b_act. One block.
__global__ void prep_small(const unsigned int* __restrict__ x,
                           const void* __restrict__ a1, const void* __restrict__ a2,
                           const void* __restrict__ bact,
                           unsigned short* __restrict__ a1b,
                           unsigned short* __restrict__ a2b,
                           unsigned short* __restrict__ bactb,
                           int* __restrict__ flag) {
    __shared__ int sflag;
    int tid = threadIdx.x;
    if (tid < 64) {
        unsigned int wv = x[tid];
        unsigned int e = (wv >> 7) & 0xFF;
        unsigned long long m = __ballot(e >= 100 && e <= 140);
        if (tid == 0) { sflag = (__popcll(m) >= 48) ? 1 : 0; flag[0] = sflag; }
    }
    __syncthreads();
    int f = sflag;
    if (tid < 128) cvt8(a1, a1b, f, tid);
    else           cvt8(a2, a2b, f, tid - 128);
    if (tid < 8)   cvt8(bact, bactb, f, tid);
}

// Convert x (8.4M elems) to bf16, 8 per thread.
__global__ void conv8(const void* __restrict__ in, unsigned short* __restrict__ out,
                      const int* __restrict__ flag, int total8) {
    int i = blockIdx.x * 256 + threadIdx.x;
    if (i >= total8) return;
    cvt8(in, out, *flag, i);
}

// Zero f1/f2 (256KB contiguous) before k1b's atomics.
__global__ void zero_kern(float4* __restrict__ p) {
    p[blockIdx.x * 256 + threadIdx.x] = float4{0.f, 0.f, 0.f, 0.f};
}

// LDS-tiled transpose + convert for W (z<4, C=256) and W_act (z==4, C=64).
__global__ __launch_bounds__(256) void t2_all(
        const void* __restrict__ Win, const void* __restrict__ Wactin,
        unsigned short* __restrict__ WT, unsigned short* __restrict__ WactT,
        const int* __restrict__ flag) {
    __shared__ unsigned int tile[64 * 65];
    int z = blockIdx.z;
    const void* in; unsigned short* out; int C, bt;
    if (z < 4) { in = Win; out = WT; C = 256; bt = z; }
    else { if (blockIdx.x != 0) return; in = Wactin; out = WactT; C = 64; bt = 0; }
    int t = threadIdx.x;
    int c0 = blockIdx.x * 64;
    int r0 = blockIdx.y * 64;
    int rl = t >> 2;
    int cc = (t & 3) * 16;
    size_t ibase = ((size_t)bt * 1024 + (r0 + rl)) * C + c0 + cc;
    unsigned short v[16];
    if (*flag) {
        const unsigned short* p = (const unsigned short*)in + ibase;
        short8 a = *(const short8*)p;
        short8 b = *(const short8*)(p + 8);
#pragma unroll
        for (int j = 0; j < 8; j++) { v[j] = (unsigned short)a[j]; v[8 + j] = (unsigned short)b[j]; }
    } else {
        const float* p = (const float*)in + ibase;
#pragma unroll
        for (int j = 0; j < 16; j++) v[j] = f2b(p[j]);
    }
#pragma unroll
    for (int j = 0; j < 16; j++)
        tile[(cc + j) * 65 + rl] = v[j];
    __syncthreads();
    int cl = t >> 2;
    int rch = (t & 3) * 16;
    unsigned short o[16];
#pragma unroll
    for (int j = 0; j < 16; j++)
        o[j] = (unsigned short)tile[cl * 65 + rch + j];
    unsigned short* op = out + ((size_t)bt * C + (c0 + cl)) * 1024 + r0 + rch;
#pragma unroll
    for (int q = 0; q < 4; q++) {
        ushort4 s; s.x = o[q*4]; s.y = o[q*4+1]; s.z = o[q*4+2]; s.w = o[q*4+3];
        ((ushort4*)op)[q] = s;
    }
}

// Pack adj into TRANSPOSED bitmask maskT[b][mword=m>>5][n] (u32), via ballot.
__global__ void pack_adj(const int* __restrict__ adj,
                         unsigned int* __restrict__ maskT) {
    int gid = blockIdx.x * 256 + threadIdx.x;
    int lane = threadIdx.x & 63;
    unsigned long long m = __ballot(adj[gid] > 0);
    if (lane == 0) {
        int lin = gid >> 6;           // (b*1024+n)*16 + m0/64
        int mw = (lin & 15) * 2;
        int bn = lin >> 4;
        int b = bn >> 10, n = bn & 1023;
        maskT[(size_t)(b * 32 + mw) * 1024 + n]     = (unsigned int)m;
        maskT[(size_t)(b * 32 + mw + 1) * 1024 + n] = (unsigned int)(m >> 32);
    }
}

// K1: Wh = x @ W[h]  (M=8192, N=1024=H*E, K=1024), writes WhF frag-tile bf16.
__global__ __launch_bounds__(256) void k1_gemm(
        const unsigned short* __restrict__ x,
        const unsigned short* __restrict__ WT,      // [H][E=256][K=1024]
        unsigned short* __restrict__ WhF) {
    __shared__ unsigned short smA[8 * 512];
    __shared__ unsigned short smB[8 * 512];
    int tid = threadIdx.x;
    int w = tid >> 6, lane = tid & 63;
    int lr = lane & 15, lq = lane >> 4;
    int col0 = blockIdx.x * 128;
    int row0 = blockIdx.y * 128;
    int h = col0 >> 8;
    int e_base = col0 & 255;
    int b = row0 >> 10;
    int m_base = row0 & 1023;
    int wr = w >> 1, wc = w & 1;

    f32x4 acc[4][4] = {};

    for (int k0 = 0; k0 < 1024; k0 += 32) {
        __syncthreads();
#pragma unroll
        for (int s = 0; s < 2; s++) {
            int g = 2 * w + s;
            const unsigned short* srcA =
                x + (size_t)(row0 + g * 16 + lr) * 1024 + k0 + lq * 8;
            glds16(srcA, &smA[g * 512]);
            const unsigned short* srcB =
                WT + (size_t)(h * 256 + e_base + g * 16 + lr) * 1024 + k0 + lq * 8;
            glds16(srcB, &smB[g * 512]);
        }
        __syncthreads();
        short8 af[4], bf[4];
#pragma unroll
        for (int i = 0; i < 4; i++)
            af[i] = *(const short8*)&smA[(wr * 4 + i) * 512 + lane * 8];
#pragma unroll
        for (int j = 0; j < 4; j++)
            bf[j] = *(const short8*)&smB[(wc * 4 + j) * 512 + lane * 8];
#pragma unroll
        for (int i = 0; i < 4; i++)
#pragma unroll
            for (int j = 0; j < 4; j++)
                acc[i][j] = __builtin_amdgcn_mfma_f32_16x16x32_bf16(
                    af[i], bf[j], acc[i][j], 0, 0, 0);
    }

    // Epilogue into frag-tile layout. Lane holds e fixed, m = tile + lq*4 + reg.
    int hb = h * 8 + b;
#pragma unroll
    for (int i = 0; i < 4; i++) {
#pragma unroll
        for (int j = 0; j < 4; j++) {
            int e = e_base + (wc * 4 + j) * 16 + lr;
            int et = e >> 5, e31 = e & 31;
            int m16 = (m_base >> 4) + wr * 4 + i;
            ushort4 vs;
            vs.x = f2b(acc[i][j][0]);
            vs.y = f2b(acc[i][j][1]);
            vs.z = f2b(acc[i][j][2]);
            vs.w = f2b(acc[i][j][3]);
            size_t idx = ((size_t)((hb * 8 + et) * 64 + m16) * 512)
                         + ((lq >> 1) * 32 + e31) * 8 + (lq & 1) * 4;
            *(ushort4*)&WhF[idx] = vs;
        }
    }
}

// K1b: f1/f2 via frag-tile coalesced short8 loads + float atomics.
// Grid (echunk=4, hb=32), block 128: thread t owns 8 consecutive m (one b128
// per e). Outputs pre-scaled by log2(e) so K2 can use native exp2.
__global__ void k1b_f12(const unsigned short* __restrict__ WhF,
                        const unsigned short* __restrict__ a1,
                        const unsigned short* __restrict__ a2,
                        float* __restrict__ f1, float* __restrict__ f2) {
    int hb = blockIdx.y;
    int ec = blockIdx.x;              // e-chunk of 64
    int t = threadIdx.x;              // 0..127 -> m = t*8 .. t*8+7
    int h = hb >> 3;
    const unsigned short* base = WhF + (size_t)hb * 8 * 64 * 512
        + (size_t)(t >> 1) * 512 + ((t & 1) * 32) * 8;
    float s1[8] = {}, s2[8] = {};
    for (int ee = 0; ee < 64; ee++) {
        int e = ec * 64 + ee;
        int et = e >> 5, e31 = e & 31;
        float a1e = b2f(a1[h * 256 + e]);
        float a2e = b2f(a2[h * 256 + e]);
        short8 v = *(const short8*)(base + (size_t)(et * 64) * 512 + e31 * 8);
#pragma unroll
        for (int j = 0; j < 8; j++) {
            float wv = b2f((unsigned short)v[j]);
            s1[j] += wv * a1e;
            s2[j] += wv * a2e;
        }
    }
    const float LOG2E = 1.44269504f;
#pragma unroll
    for (int j = 0; j < 8; j++) {
        atomicAdd(&f1[hb * 1024 + t * 8 + j], s1[j] * LOG2E);
        atomicAdd(&f2[hb * 1024 + t * 8 + j], s2[j] * LOG2E);
    }
}

// K2: masked-softmax attention + P@Wh + ELU -> feat[bn][h*256+e] bf16.
// Dedup: wave = 32 rows x ALL 256 e (8 acc tiles, 128 AGPR), p computed ONCE
// per (row,m). m split in halves across wave pairs for occupancy (2048 waves
// = 2/SIMD); partial acc+den combined via one LDS exchange at the end.
// K-loop stays barrier-free; B-frags are contiguous 1KB tiles (coalesced,
// L2-resident via XCD swizzle). f1/f2 pre-scaled by log2e -> native exp2.
__global__ __launch_bounds__(256, 2) void k2_attn(
        const unsigned short* __restrict__ WhF,
        const unsigned int* __restrict__ maskT,     // [8][32][1024]
        const float* __restrict__ f1, const float* __restrict__ f2,
        unsigned short* __restrict__ feat) {
    __shared__ float cmb[4][64][65];                // acc exchange (pad: no bank dup)
    __shared__ float dend[4][32];
    int tid = threadIdx.x;
    int w = tid >> 6, lane = tid & 63;
    int l5 = lane >> 5, l31 = lane & 31;
    int bid = blockIdx.x;
    int xcd = bid & 7, idx = bid >> 3;              // idx 0..63
    int hb = xcd + 8 * (idx >> 4);
    int pair = idx & 15;
    int rg = pair * 2 + (w & 1);                    // row-group 0..31
    int mh = w >> 1;                                // m-half 0/1
    int n0 = rg * 32;
    int h = hb >> 3, b = hb & 7;
    int row = n0 + l31;
    float f1n = f1[hb * 1024 + row];                // already *log2e
    const unsigned short* whb = WhF + (size_t)hb * 8 * 64 * 512 + lane * 8;
    const unsigned int* mrow = maskT + (size_t)b * 32 * 1024 + row;
    const float* f2row = f2 + hb * 1024;

    f32x16 acc[8] = {};                             // et tile: e = et*32 + l31
    float den = 0.f;

    int m_lo = mh * 512, m_hi = m_lo + 512;
    for (int m0 = m_lo; m0 < m_hi; m0 += 32) {
        int m16 = m0 >> 4;
        // 16 coalesced 1KB frag loads (issue first; p-compute hides latency)
        short8 fr[8][2];
#pragma unroll
        for (int et = 0; et < 8; et++)
#pragma unroll
            for (int ks = 0; ks < 2; ks++)
                fr[et][ks] = *(const short8*)(whb + (size_t)(et * 64 + m16 + ks) * 512);

        unsigned int mws = mrow[(size_t)(m0 >> 5) * 1024] >> (l5 * 8);
        float4 fA0 = *(const float4*)(f2row + m0 + l5 * 8);
        float4 fA1 = *(const float4*)(f2row + m0 + l5 * 8 + 4);
        float4 fB0 = *(const float4*)(f2row + m0 + 16 + l5 * 8);
        float4 fB1 = *(const float4*)(f2row + m0 + 16 + l5 * 8 + 4);
        float fm[16] = {fA0.x,fA0.y,fA0.z,fA0.w, fA1.x,fA1.y,fA1.z,fA1.w,
                        fB0.x,fB0.y,fB0.z,fB0.w, fB1.x,fB1.y,fB1.z,fB1.w};
        union { unsigned int u[4]; short8 v; } af[2];
#pragma unroll
        for (int ks = 0; ks < 2; ks++) {
#pragma unroll
            for (int pr = 0; pr < 4; pr++) {
                unsigned int ub[2];
#pragma unroll
                for (int q = 0; q < 2; q++) {
                    int j = pr * 2 + q;
                    float tL = f1n + fm[ks * 8 + j];       // log2-domain logit
                    float eL = fmaxf(tL, 0.2f * tL);       // leaky relu
                    float pv = ((mws >> (ks * 16 + j)) & 1u) ? exp2f(eL) : 0.f;
                    union { float f; unsigned int i; } pu; pu.f = pv;
                    ub[q] = pu.i & 0xFFFF0000u;            // bf16 (truncate)
                    union { unsigned int i; float f; } tb; tb.i = ub[q];
                    den += tb.f;                           // consistent num/den
                }
                af[ks].u[pr] = (ub[0] >> 16) | ub[1];
            }
        }
#pragma unroll
        for (int et = 0; et < 8; et++)
#pragma unroll
            for (int ks = 0; ks < 2; ks++)
                acc[et] = __builtin_amdgcn_mfma_f32_32x32x16_bf16(
                    af[ks].v, fr[et][ks], acc[et], 0, 0, 0);
    }

    // intra-wave: combine l5 halves of den (lanes r and r+32 -> row r total)
    den += __shfl_xor(den, 32, 64);

    // cross-wave m-half combine via LDS. Wave gives away 4 et tiles, keeps 4.
    // mh0 keeps et0..3 (gives 4..7); mh1 keeps et4..7 (gives 0..3).
    int give = (mh == 0) ? 4 : 0;
    int keep = (mh == 0) ? 0 : 4;
#pragma unroll
    for (int t = 0; t < 4; t++)
#pragma unroll
        for (int reg = 0; reg < 16; reg++)
            cmb[w][lane][t * 16 + reg] = acc[give + t][reg];
    if (lane < 32) dend[w][l31] = den;
    __syncthreads();
    int pw = w ^ 2;
    float den_tot = den + dend[pw][l31];
    float rdr_all[16];
#pragma unroll
    for (int reg = 0; reg < 16; reg++) {
        int r = (reg & 3) + 8 * (reg >> 2) + 4 * l5;   // C-layout row (0..31)
        rdr_all[reg] = 1.0f / __shfl(den_tot, r, 64);
    }
#pragma unroll
    for (int t = 0; t < 4; t++) {
        int et = keep + t;
        int e = et * 32 + l31;
#pragma unroll
        for (int reg = 0; reg < 16; reg++) {
            int r = (reg & 3) + 8 * (reg >> 2) + 4 * l5;
            float v = (acc[et][reg] + cmb[pw][lane][t * 16 + reg]) * rdr_all[reg];
            float o = v > 0.f ? v : __expf(v) - 1.f;   // elu
            feat[(size_t)(b * 1024 + n0 + r) * 1024 + h * 256 + e] = f2b(o);
        }
    }
}

// K3: out = feat @ W_act + b_act  (M=8192, K=1024, N=64), out dtype per flag.
__global__ __launch_bounds__(256) void k3_out(
        const unsigned short* __restrict__ feat,
        const unsigned short* __restrict__ WactT,   // [64][1024]
        const unsigned short* __restrict__ bact,
        void* __restrict__ out, const int* __restrict__ flag) {
    __shared__ unsigned short smA[2 * 512];
    __shared__ unsigned short smB[4 * 512];
    int tid = threadIdx.x;
    int w = tid >> 6, lane = tid & 63;
    int lr = lane & 15, lq = lane >> 4;
    int row0 = blockIdx.x * 32;
    int g = w & 1, ch = w >> 1;
    int bf16out = *flag;
    f32x4 acc[2] = {};

    for (int k0 = 0; k0 < 1024; k0 += 32) {
        __syncthreads();
        if (w < 2) {
            const unsigned short* src =
                feat + (size_t)(row0 + w * 16 + lr) * 1024 + k0 + lq * 8;
            glds16(src, &smA[w * 512]);
        } else {
#pragma unroll
            for (int s = 0; s < 2; s++) {
                int t = (w - 2) * 2 + s;
                const unsigned short* src =
                    WactT + (size_t)(t * 16 + lr) * 1024 + k0 + lq * 8;
                glds16(src, &smB[t * 512]);
            }
        }
        __syncthreads();
        short8 af = *(const short8*)&smA[g * 512 + lane * 8];
#pragma unroll
        for (int j = 0; j < 2; j++) {
            short8 bf = *(const short8*)&smB[(ch * 2 + j) * 512 + lane * 8];
            acc[j] = __builtin_amdgcn_mfma_f32_16x16x32_bf16(af, bf, acc[j], 0, 0, 0);
        }
    }
#pragma unroll
    for (int j = 0; j < 2; j++) {
        int col = ch * 32 + j * 16 + lr;
        float bv = b2f(bact[col]);
#pragma unroll
        for (int rr = 0; rr < 4; rr++) {
            int r = row0 + g * 16 + lq * 4 + rr;
            float val = acc[j][rr] + bv;
            if (bf16out) ((unsigned short*)out)[(size_t)r * 64 + col] = f2b(val);
            else         ((float*)out)[(size_t)r * 64 + col] = val;
        }
    }
}

extern "C" void kernel_launch(void* const* d_in, const int* in_sizes, int n_in,
                              void* d_out, int out_size, void* d_ws, size_t ws_size,
                              hipStream_t stream) {
    const void* x    = d_in[0];
    const int*  adj  = (const int*)d_in[1];
    const void* W    = d_in[2];
    const void* a1   = d_in[3];
    const void* a2   = d_in[4];
    const void* Wact = d_in[5];
    const void* bact = d_in[6];

    char* ws = (char*)d_ws;
    unsigned short* WhF   = (unsigned short*)(ws);               // 16 MB  frag-tile
    unsigned short* xb    = (unsigned short*)(ws + 16777216);    // 16 MB  (== feat)
    unsigned short* feat  = (unsigned short*)(ws + 16777216);    // 16 MB  [8192][1024]
    unsigned short* WT    = (unsigned short*)(ws + 33554432);    //  2 MB  [4][256][1024]
    unsigned int*   maskT = (unsigned int*)(ws + 33554432);      //  1 MB  (== WT, after k1)
    unsigned short* WactT = (unsigned short*)(ws + 35651584);    // 128 KB [64][1024]
    float*          f1    = (float*)(ws + 35782656);             // 128 KB [32][1024]
    float*          f2    = (float*)(ws + 35913728);             // 128 KB [32][1024]
    unsigned short* a1b   = (unsigned short*)(ws + 36044800);    // 2 KB
    unsigned short* a2b   = (unsigned short*)(ws + 36046848);    // 2 KB
    unsigned short* bactb = (unsigned short*)(ws + 36048896);    // 128 B
    int*            flag  = (int*)(ws + 36049024);               // 16 B
    if (ws_size < (size_t)36049040) return;

    prep_small<<<1, 256, 0, stream>>>((const unsigned int*)x, a1, a2, bact,
                                      a1b, a2b, bactb, flag);
    conv8<<<4096, 256, 0, stream>>>(x, xb, flag, 1048576);
    t2_all<<<dim3(4, 16, 5), 256, 0, stream>>>(W, Wact, WT, WactT, flag);
    zero_kern<<<64, 256, 0, stream>>>((float4*)f1);   // zeroes f1+f2 (256KB)
    k1_gemm<<<dim3(8, 64), 256, 0, stream>>>(xb, WT, WhF);
    pack_adj<<<32768, 256, 0, stream>>>(adj, maskT);   // overwrites WT (dead)
    k1b_f12<<<dim3(4, 32), 128, 0, stream>>>(WhF, a1b, a2b, f1, f2);
    k2_attn<<<512, 256, 0, stream>>>(WhF, maskT, f1, f2, feat);
    k3_out<<<256, 256, 0, stream>>>(feat, WactT, bactb, d_out, flag);
}

// Round 8
// 230.253 us; speedup vs baseline: 1.0829x; 1.0829x over previous
//
#include <hip/hip_runtime.h>
#include <stdint.h>

// Problem constants: B=8, N=1024, IN_F=1024, E=256, H=4, A=64
typedef __attribute__((ext_vector_type(8))) short short8;
typedef __attribute__((ext_vector_type(4))) float f32x4;
typedef __attribute__((ext_vector_type(16))) float f32x16;

// WhF frag-tile layout (canonical, used by k1 epilogue and k2):
//   element (hb, e, m), e in [0,256), m in [0,1024):
//   et=e>>5, e31=e&31, m16=m>>4, l5=(m>>3)&1, m7=m&7
//   u16 idx = ((hb*8+et)*64 + m16)*512 + (l5*32+e31)*8 + m7
// => one (et,m16) tile is 1KB contiguous in MFMA-B lane order (lane=l5*32+e31).

__device__ __forceinline__ float b2f(unsigned short u) {
    union { unsigned int i; float f; } v; v.i = ((unsigned int)u) << 16; return v.f;
}
__device__ __forceinline__ unsigned short f2b(float f) {
    union { float f; unsigned int i; } v; v.f = f;
    unsigned int u = v.i;
    u = (u + 0x7FFFu + ((u >> 16) & 1u)) >> 16;
    return (unsigned short)u;
}
__device__ __forceinline__ void glds16(const void* g, const void* l) {
    __builtin_amdgcn_global_load_lds(
        (const __attribute__((address_space(1))) unsigned int*)g,
        (__attribute__((address_space(3))) unsigned int*)l, 16, 0, 0);
}

__device__ __forceinline__ void cvt8(const void* in, unsigned short* out,
                                     int f, int grp) {
    if (f) {
        ((ushort4*)out)[grp * 2]     = ((const ushort4*)in)[grp * 2];
        ((ushort4*)out)[grp * 2 + 1] = ((const ushort4*)in)[grp * 2 + 1];
    } else {
        const float4* p = (const float4*)in + (size_t)grp * 2;
        float4 a = p[0], b = p[1];
        ushort4 o0, o1;
        o0.x = f2b(a.x); o0.y = f2b(a.y); o0.z = f2b(a.z); o0.w = f2b(a.w);
        o1.x = f2b(b.x); o1.y = f2b(b.y); o1.z = f2b(b.z); o1.w = f2b(b.w);
        ((ushort4*)out)[grp * 2]     = o0;
        ((ushort4*)out)[grp * 2 + 1] = o1;
    }
}

// prep_small: dtype detect (wave 0) + convert a1/a2/b_act. One block.
__global__ void prep_small(const unsigned int* __restrict__ x,
                           const void* __restrict__ a1, const void* __restrict__ a2,
                           const void* __restrict__ bact,
                           unsigned short* __restrict__ a1b,
                           unsigned short* __restrict__ a2b,
                           unsigned short* __restrict__ bactb,
                           int* __restrict__ flag) {
    __shared__ int sflag;
    int tid = threadIdx.x;
    if (tid < 64) {
        unsigned int wv = x[tid];
        unsigned int e = (wv >> 7) & 0xFF;
        unsigned long long m = __ballot(e >= 100 && e <= 140);
        if (tid == 0) { sflag = (__popcll(m) >= 48) ? 1 : 0; flag[0] = sflag; }
    }
    __syncthreads();
    int f = sflag;
    if (tid < 128) cvt8(a1, a1b, f, tid);
    else           cvt8(a2, a2b, f, tid - 128);
    if (tid < 8)   cvt8(bact, bactb, f, tid);
}

// Convert x (8.4M elems) to bf16, 8 per thread.
__global__ void conv8(const void* __restrict__ in, unsigned short* __restrict__ out,
                      const int* __restrict__ flag, int total8) {
    int i = blockIdx.x * 256 + threadIdx.x;
    if (i >= total8) return;
    cvt8(in, out, *flag, i);
}

// Zero f1/f2 (256KB contiguous) before k1's epilogue atomics.
__global__ void zero_kern(float4* __restrict__ p) {
    p[blockIdx.x * 256 + threadIdx.x] = float4{0.f, 0.f, 0.f, 0.f};
}

// LDS-tiled transpose + convert for W (z<4, C=256) and W_act (z==4, C=64).
__global__ __launch_bounds__(256) void t2_all(
        const void* __restrict__ Win, const void* __restrict__ Wactin,
        unsigned short* __restrict__ WT, unsigned short* __restrict__ WactT,
        const int* __restrict__ flag) {
    __shared__ unsigned int tile[64 * 65];
    int z = blockIdx.z;
    const void* in; unsigned short* out; int C, bt;
    if (z < 4) { in = Win; out = WT; C = 256; bt = z; }
    else { if (blockIdx.x != 0) return; in = Wactin; out = WactT; C = 64; bt = 0; }
    int t = threadIdx.x;
    int c0 = blockIdx.x * 64;
    int r0 = blockIdx.y * 64;
    int rl = t >> 2;
    int cc = (t & 3) * 16;
    size_t ibase = ((size_t)bt * 1024 + (r0 + rl)) * C + c0 + cc;
    unsigned short v[16];
    if (*flag) {
        const unsigned short* p = (const unsigned short*)in + ibase;
        short8 a = *(const short8*)p;
        short8 b = *(const short8*)(p + 8);
#pragma unroll
        for (int j = 0; j < 8; j++) { v[j] = (unsigned short)a[j]; v[8 + j] = (unsigned short)b[j]; }
    } else {
        const float* p = (const float*)in + ibase;
#pragma unroll
        for (int j = 0; j < 16; j++) v[j] = f2b(p[j]);
    }
#pragma unroll
    for (int j = 0; j < 16; j++)
        tile[(cc + j) * 65 + rl] = v[j];
    __syncthreads();
    int cl = t >> 2;
    int rch = (t & 3) * 16;
    unsigned short o[16];
#pragma unroll
    for (int j = 0; j < 16; j++)
        o[j] = (unsigned short)tile[cl * 65 + rch + j];
    unsigned short* op = out + ((size_t)bt * C + (c0 + cl)) * 1024 + r0 + rch;
#pragma unroll
    for (int q = 0; q < 4; q++) {
        ushort4 s; s.x = o[q*4]; s.y = o[q*4+1]; s.z = o[q*4+2]; s.w = o[q*4+3];
        ((ushort4*)op)[q] = s;
    }
}

// Pack adj into TRANSPOSED bitmask maskT[b][mword=m>>5][n] (u32), via ballot.
__global__ void pack_adj(const int* __restrict__ adj,
                         unsigned int* __restrict__ maskT) {
    int gid = blockIdx.x * 256 + threadIdx.x;
    int lane = threadIdx.x & 63;
    unsigned long long m = __ballot(adj[gid] > 0);
    if (lane == 0) {
        int lin = gid >> 6;           // (b*1024+n)*16 + m0/64
        int mw = (lin & 15) * 2;
        int bn = lin >> 4;
        int b = bn >> 10, n = bn & 1023;
        maskT[(size_t)(b * 32 + mw) * 1024 + n]     = (unsigned int)m;
        maskT[(size_t)(b * 32 + mw + 1) * 1024 + n] = (unsigned int)(m >> 32);
    }
}

// K1: Wh = x @ W[h] -> WhF frag-tile bf16. Epilogue also accumulates
// f1 = Wh.a1, f2 = Wh.a2 (pre-scaled by log2e) via shfl-reduce + atomics,
// replacing the separate (latency-bound) k1b kernel.
__global__ __launch_bounds__(256) void k1_gemm(
        const unsigned short* __restrict__ x,
        const unsigned short* __restrict__ WT,      // [H][E=256][K=1024]
        unsigned short* __restrict__ WhF,
        const unsigned short* __restrict__ a1b,
        const unsigned short* __restrict__ a2b,
        float* __restrict__ f1, float* __restrict__ f2) {
    __shared__ unsigned short smA[8 * 512];
    __shared__ unsigned short smB[8 * 512];
    int tid = threadIdx.x;
    int w = tid >> 6, lane = tid & 63;
    int lr = lane & 15, lq = lane >> 4;
    int col0 = blockIdx.x * 128;
    int row0 = blockIdx.y * 128;
    int h = col0 >> 8;
    int e_base = col0 & 255;
    int b = row0 >> 10;
    int m_base = row0 & 1023;
    int wr = w >> 1, wc = w & 1;

    f32x4 acc[4][4] = {};

    for (int k0 = 0; k0 < 1024; k0 += 32) {
        __syncthreads();
#pragma unroll
        for (int s = 0; s < 2; s++) {
            int g = 2 * w + s;
            const unsigned short* srcA =
                x + (size_t)(row0 + g * 16 + lr) * 1024 + k0 + lq * 8;
            glds16(srcA, &smA[g * 512]);
            const unsigned short* srcB =
                WT + (size_t)(h * 256 + e_base + g * 16 + lr) * 1024 + k0 + lq * 8;
            glds16(srcB, &smB[g * 512]);
        }
        __syncthreads();
        short8 af[4], bf[4];
#pragma unroll
        for (int i = 0; i < 4; i++)
            af[i] = *(const short8*)&smA[(wr * 4 + i) * 512 + lane * 8];
#pragma unroll
        for (int j = 0; j < 4; j++)
            bf[j] = *(const short8*)&smB[(wc * 4 + j) * 512 + lane * 8];
#pragma unroll
        for (int i = 0; i < 4; i++)
#pragma unroll
            for (int j = 0; j < 4; j++)
                acc[i][j] = __builtin_amdgcn_mfma_f32_16x16x32_bf16(
                    af[i], bf[j], acc[i][j], 0, 0, 0);
    }

    // Epilogue 1: WhF frag-tile stores. Lane: e fixed, m = tile + lq*4 + reg.
    int hb = h * 8 + b;
#pragma unroll
    for (int i = 0; i < 4; i++) {
#pragma unroll
        for (int j = 0; j < 4; j++) {
            int e = e_base + (wc * 4 + j) * 16 + lr;
            int et = e >> 5, e31 = e & 31;
            int m16 = (m_base >> 4) + wr * 4 + i;
            ushort4 vs;
            vs.x = f2b(acc[i][j][0]);
            vs.y = f2b(acc[i][j][1]);
            vs.z = f2b(acc[i][j][2]);
            vs.w = f2b(acc[i][j][3]);
            size_t idx = ((size_t)((hb * 8 + et) * 64 + m16) * 512)
                         + ((lq >> 1) * 32 + e31) * 8 + (lq & 1) * 4;
            *(ushort4*)&WhF[idx] = vs;
        }
    }

    // Epilogue 2: f1/f2 partials. Lane's 4 e-values (one per j), 16 m (i,reg).
    const float LOG2E = 1.44269504f;
    float a1v[4], a2v[4];
#pragma unroll
    for (int j = 0; j < 4; j++) {
        int e = e_base + (wc * 4 + j) * 16 + lr;
        a1v[j] = b2f(a1b[h * 256 + e]);
        a2v[j] = b2f(a2b[h * 256 + e]);
    }
#pragma unroll
    for (int i = 0; i < 4; i++) {
#pragma unroll
        for (int reg = 0; reg < 4; reg++) {
            float s1 = 0.f, s2 = 0.f;
#pragma unroll
            for (int j = 0; j < 4; j++) {
                s1 += acc[i][j][reg] * a1v[j];
                s2 += acc[i][j][reg] * a2v[j];
            }
            // reduce over lr (16-lane groups; xor<16 stays in group)
            s1 += __shfl_xor(s1, 1, 64); s2 += __shfl_xor(s2, 1, 64);
            s1 += __shfl_xor(s1, 2, 64); s2 += __shfl_xor(s2, 2, 64);
            s1 += __shfl_xor(s1, 4, 64); s2 += __shfl_xor(s2, 4, 64);
            s1 += __shfl_xor(s1, 8, 64); s2 += __shfl_xor(s2, 8, 64);
            if (lr == 0) {
                int m = m_base + (wr * 4 + i) * 16 + lq * 4 + reg;
                atomicAdd(&f1[hb * 1024 + m], s1 * LOG2E);
                atomicAdd(&f2[hb * 1024 + m], s2 * LOG2E);
            }
        }
    }
}

// K2: masked-softmax attention + P@Wh + ELU -> feat[bn][h*256+e] bf16.
// Full dedup, barrier-free, zero LDS: wave = 32 rows x ALL 256 e x ALL 1024 m.
// acc 128 + frag 64 + temps ~ 250 regs; launch_bounds(256,1) lifts the cap to
// 512 so NOTHING spills (r7's 148MB WRITE_SIZE was spill traffic at cap=256).
// 1024 waves, 4 independent waves/block (same hb -> L1 cross-wave tile hits).
// B-frags are contiguous 1KB tiles (coalesced, L2-resident via XCD swizzle).
// f1/f2 pre-scaled by log2e -> native exp2.
__global__ __launch_bounds__(256, 1) void k2_attn(
        const unsigned short* __restrict__ WhF,
        const unsigned int* __restrict__ maskT,     // [8][32][1024]
        const float* __restrict__ f1, const float* __restrict__ f2,
        unsigned short* __restrict__ feat) {
    int tid = threadIdx.x;
    int w = tid >> 6, lane = tid & 63;
    int l5 = lane >> 5, l31 = lane & 31;
    int bid = blockIdx.x;                           // 256 blocks
    int xcd = bid & 7, idx = bid >> 3;              // idx 0..31
    int hb = xcd + 8 * (idx >> 3);                  // 4 hb per xcd
    int rg = (idx & 7) * 4 + w;                     // row-group 0..31
    int n0 = rg * 32;
    int h = hb >> 3, b = hb & 7;
    int row = n0 + l31;
    float f1n = f1[hb * 1024 + row];                // already *log2e
    const unsigned short* whb = WhF + (size_t)hb * 8 * 64 * 512 + lane * 8;
    const unsigned int* mrow = maskT + (size_t)b * 32 * 1024 + row;
    const float* f2row = f2 + hb * 1024;

    f32x16 acc[8] = {};                             // et tile: e = et*32 + l31
    float den = 0.f;

    for (int m0 = 0; m0 < 1024; m0 += 32) {
        int m16 = m0 >> 4;
        // 16 coalesced 1KB frag loads (issue first; p-compute hides latency)
        short8 fr[8][2];
#pragma unroll
        for (int et = 0; et < 8; et++)
#pragma unroll
            for (int ks = 0; ks < 2; ks++)
                fr[et][ks] = *(const short8*)(whb + (size_t)(et * 64 + m16 + ks) * 512);

        unsigned int mw = mrow[(size_t)(m0 >> 5) * 1024];
        float4 fA0 = *(const float4*)(f2row + m0 + l5 * 8);
        float4 fA1 = *(const float4*)(f2row + m0 + l5 * 8 + 4);
        float4 fB0 = *(const float4*)(f2row + m0 + 16 + l5 * 8);
        float4 fB1 = *(const float4*)(f2row + m0 + 16 + l5 * 8 + 4);
        float fm[16] = {fA0.x,fA0.y,fA0.z,fA0.w, fA1.x,fA1.y,fA1.z,fA1.w,
                        fB0.x,fB0.y,fB0.z,fB0.w, fB1.x,fB1.y,fB1.z,fB1.w};
        union { unsigned int u[4]; short8 v; } af[2];
#pragma unroll
        for (int ks = 0; ks < 2; ks++) {
#pragma unroll
            for (int pr = 0; pr < 4; pr++) {
                unsigned int ub[2];
#pragma unroll
                for (int q = 0; q < 2; q++) {
                    int j = pr * 2 + q;
                    float tL = f1n + fm[ks * 8 + j];       // log2-domain logit
                    float eL = fmaxf(tL, 0.2f * tL);       // leaky relu
                    float pv = ((mw >> (ks * 16 + l5 * 8 + j)) & 1u)
                                   ? exp2f(eL) : 0.f;
                    union { float f; unsigned int i; } pu; pu.f = pv;
                    ub[q] = pu.i & 0xFFFF0000u;            // bf16 (truncate)
                    union { unsigned int i; float f; } tb; tb.i = ub[q];
                    den += tb.f;                           // consistent num/den
                }
                af[ks].u[pr] = (ub[0] >> 16) | ub[1];
            }
        }
#pragma unroll
        for (int et = 0; et < 8; et++)
#pragma unroll
            for (int ks = 0; ks < 2; ks++)
                acc[et] = __builtin_amdgcn_mfma_f32_32x32x16_bf16(
                    af[ks].v, fr[et][ks], acc[et], 0, 0, 0);
    }

    // den: lane holds partial for row l31 over its k-half; combine halves
    den += __shfl_xor(den, 32, 64);

    float rdr_all[16];
#pragma unroll
    for (int reg = 0; reg < 16; reg++) {
        int r = (reg & 3) + 8 * (reg >> 2) + 4 * l5;   // C-layout row (0..31)
        rdr_all[reg] = 1.0f / __shfl(den, r, 64);
    }
#pragma unroll
    for (int et = 0; et < 8; et++) {
        int e = et * 32 + l31;
#pragma unroll
        for (int reg = 0; reg < 16; reg++) {
            int r = (reg & 3) + 8 * (reg >> 2) + 4 * l5;
            float v = acc[et][reg] * rdr_all[reg];
            float o = v > 0.f ? v : __expf(v) - 1.f;   // elu
            feat[(size_t)(b * 1024 + n0 + r) * 1024 + h * 256 + e] = f2b(o);
        }
    }
}

// K3: out = feat @ W_act + b_act  (M=8192, K=1024, N=64), out dtype per flag.
__global__ __launch_bounds__(256) void k3_out(
        const unsigned short* __restrict__ feat,
        const unsigned short* __restrict__ WactT,   // [64][1024]
        const unsigned short* __restrict__ bact,
        void* __restrict__ out, const int* __restrict__ flag) {
    __shared__ unsigned short smA[2 * 512];
    __shared__ unsigned short smB[4 * 512];
    int tid = threadIdx.x;
    int w = tid >> 6, lane = tid & 63;
    int lr = lane & 15, lq = lane >> 4;
    int row0 = blockIdx.x * 32;
    int g = w & 1, ch = w >> 1;
    int bf16out = *flag;
    f32x4 acc[2] = {};

    for (int k0 = 0; k0 < 1024; k0 += 32) {
        __syncthreads();
        if (w < 2) {
            const unsigned short* src =
                feat + (size_t)(row0 + w * 16 + lr) * 1024 + k0 + lq * 8;
            glds16(src, &smA[w * 512]);
        } else {
#pragma unroll
            for (int s = 0; s < 2; s++) {
                int t = (w - 2) * 2 + s;
                const unsigned short* src =
                    WactT + (size_t)(t * 16 + lr) * 1024 + k0 + lq * 8;
                glds16(src, &smB[t * 512]);
            }
        }
        __syncthreads();
        short8 af = *(const short8*)&smA[g * 512 + lane * 8];
#pragma unroll
        for (int j = 0; j < 2; j++) {
            short8 bf = *(const short8*)&smB[(ch * 2 + j) * 512 + lane * 8];
            acc[j] = __builtin_amdgcn_mfma_f32_16x16x32_bf16(af, bf, acc[j], 0, 0, 0);
        }
    }
#pragma unroll
    for (int j = 0; j < 2; j++) {
        int col = ch * 32 + j * 16 + lr;
        float bv = b2f(bact[col]);
#pragma unroll
        for (int rr = 0; rr < 4; rr++) {
            int r = row0 + g * 16 + lq * 4 + rr;
            float val = acc[j][rr] + bv;
            if (bf16out) ((unsigned short*)out)[(size_t)r * 64 + col] = f2b(val);
            else         ((float*)out)[(size_t)r * 64 + col] = val;
        }
    }
}

extern "C" void kernel_launch(void* const* d_in, const int* in_sizes, int n_in,
                              void* d_out, int out_size, void* d_ws, size_t ws_size,
                              hipStream_t stream) {
    const void* x    = d_in[0];
    const int*  adj  = (const int*)d_in[1];
    const void* W    = d_in[2];
    const void* a1   = d_in[3];
    const void* a2   = d_in[4];
    const void* Wact = d_in[5];
    const void* bact = d_in[6];

    char* ws = (char*)d_ws;
    unsigned short* WhF   = (unsigned short*)(ws);               // 16 MB  frag-tile
    unsigned short* xb    = (unsigned short*)(ws + 16777216);    // 16 MB  (== feat)
    unsigned short* feat  = (unsigned short*)(ws + 16777216);    // 16 MB  [8192][1024]
    unsigned short* WT    = (unsigned short*)(ws + 33554432);    //  2 MB  [4][256][1024]
    unsigned int*   maskT = (unsigned int*)(ws + 33554432);      //  1 MB  (== WT, after k1)
    unsigned short* WactT = (unsigned short*)(ws + 35651584);    // 128 KB [64][1024]
    float*          f1    = (float*)(ws + 35782656);             // 128 KB [32][1024]
    float*          f2    = (float*)(ws + 35913728);             // 128 KB [32][1024]
    unsigned short* a1b   = (unsigned short*)(ws + 36044800);    // 2 KB
    unsigned short* a2b   = (unsigned short*)(ws + 36046848);    // 2 KB
    unsigned short* bactb = (unsigned short*)(ws + 36048896);    // 128 B
    int*            flag  = (int*)(ws + 36049024);               // 16 B
    if (ws_size < (size_t)36049040) return;

    prep_small<<<1, 256, 0, stream>>>((const unsigned int*)x, a1, a2, bact,
                                      a1b, a2b, bactb, flag);
    conv8<<<4096, 256, 0, stream>>>(x, xb, flag, 1048576);
    t2_all<<<dim3(4, 16, 5), 256, 0, stream>>>(W, Wact, WT, WactT, flag);
    zero_kern<<<64, 256, 0, stream>>>((float4*)f1);   // zeroes f1+f2 (256KB)
    k1_gemm<<<dim3(8, 64), 256, 0, stream>>>(xb, WT, WhF, a1b, a2b, f1, f2);
    pack_adj<<<32768, 256, 0, stream>>>(adj, maskT);   // overwrites WT (dead)
    k2_attn<<<256, 256, 0, stream>>>(WhF, maskT, f1, f2, feat);
    k3_out<<<256, 256, 0, stream>>>(feat, WactT, bactb, d_out, flag);
}